// Round 10
// baseline (290.284 us; speedup 1.0000x reference)
//
#include <hip/hip_runtime.h>
#include <math.h>

// LSTMLightweight on MI355X (R10: gate-split + reg-weights + broadcast-LDS h).
//   x[B,T,1] -> linear_in(1->16)+ReLU -> LSTM0(16) -> LSTM1(16) -> fc(16->8)+ReLU -> fc(8->1)
// Ladder: R9 (EPW4, 192 weight regs) 221us — allocator demotes ~100 values to
// AGPR/remat to hit its immovable 128 arch-VGPR tier => ~430 instr/step vs 130.
// R10 designs UNDER the wall: EPW=2, 32 lanes/elem, lane (j,half) owns 2 gate
// rows -> 96 weight VGPRs, total honest pressure ~135 ~= budget -> ~no demotion.
// half0 owns rows {i:j, f:16+j} + cell state; half1 owns {g:32+j, o:48+j} and
// writes h_j. Dots: terms-packed v2f pk_fma with h via BROADCAST float4 LDS
// reads (2 distinct addrs/instr, ~issue-cost only — R5's 353us came from fat
// per-lane WEIGHT reads, not these). Combine via 2 shfl_xor(16)/layer;
// double-buffered h + 2 __syncthreads()/step (R4/R5-proven ordering).
// b_in!=0 handled by the separate self-gating guard kernel (R5 code, proven).

#define EPW 2
#define L2E 1.4426950408889634f

typedef float v2f __attribute__((ext_vector_type(2)));

__device__ __forceinline__ float sigm(float v) {
    return __builtin_amdgcn_rcpf(1.0f + __builtin_amdgcn_exp2f(-L2E * v));
}
__device__ __forceinline__ float tanh_(float v) {
    // tanh(v) = 1 - 2/(exp(2v)+1); saturates correctly at +-inf
    return 1.0f - 2.0f * __builtin_amdgcn_rcpf(1.0f + __builtin_amdgcn_exp2f((2.0f * L2E) * v));
}

__global__ __launch_bounds__(64, 2) void lstm_gsr(
    const float* __restrict__ x,
    const float* __restrict__ w_in, const float* __restrict__ b_in,
    const float* __restrict__ w_ih0, const float* __restrict__ w_hh0,
    const float* __restrict__ b_ih0, const float* __restrict__ b_hh0,
    const float* __restrict__ w_ih1, const float* __restrict__ w_hh1,
    const float* __restrict__ b_ih1, const float* __restrict__ b_hh1,
    const float* __restrict__ fc_h_w, const float* __restrict__ fc_h_b,
    const float* __restrict__ fc_o_w, const float* __restrict__ fc_o_b,
    float* __restrict__ out, int B, int T)
{
    // only handles the b_in == 0 case; guard kernel covers the rest
    bool bzero = true;
    #pragma unroll
    for (int k = 0; k < 16; ++k)
        if (b_in[k] != 0.0f) bzero = false;
    if (!bzero) return;

    const int lane = threadIdx.x;       // 0..63
    const int e    = lane >> 5;         // element in block (0..1)
    const int sub  = lane & 31;
    const int j    = sub & 15;          // hidden unit
    const int half = sub >> 4;          // 0: rows {i,f}; 1: rows {g,o}
    const int elem  = blockIdx.x * EPW + e;
    const int elemc = elem < B ? elem : B - 1;
    const int rA = half * 32 + j;       // gate row A (i or g)
    const int rB = rA + 16;             // gate row B (f or o)

    __shared__ float4 h0b[2][EPW][4];   // double-buffered h exchange (64B rows)
    __shared__ float4 h1b[2][EPW][4];
    __shared__ float  zb[EPW][8];

    // ---- weights in registers: rows rA,rB of w_hh0/w_ih1/w_hh1 as v2f pairs ----
    v2f wh0[2][8], wi1[2][8], wh1[2][8];
    float bb0[2], bb1[2], ap[2], an[2];
    #pragma unroll
    for (int g = 0; g < 2; ++g) {
        const int row = g ? rB : rA;
        const v2f* p0 = (const v2f*)(w_hh0 + row * 16);
        const v2f* p1 = (const v2f*)(w_ih1 + row * 16);
        const v2f* p2 = (const v2f*)(w_hh1 + row * 16);
        #pragma unroll
        for (int q = 0; q < 8; ++q) {
            wh0[g][q] = p0[q];
            wi1[g][q] = p1[q];
            wh1[g][q] = p2[q];
        }
        bb0[g] = b_ih0[row] + b_hh0[row];
        bb1[g] = b_ih1[row] + b_hh1[row];
        ap[g] = 0.0f; an[g] = 0.0f;
    }
    // Fold linear_in(+ReLU) through w_ih0 (b_in == 0): x>0 -> x*Ap ; x<=0 -> x*An
    #pragma unroll
    for (int k = 0; k < 16; ++k) {
        const float wk = w_in[k];
        const float wp = fmaxf(wk, 0.0f), wn = fminf(wk, 0.0f);
        #pragma unroll
        for (int g = 0; g < 2; ++g) {
            const float wg = w_ih0[(g ? rB : rA) * 16 + k];
            ap[g] = fmaf(wg, wp, ap[g]);
            an[g] = fmaf(wg, wn, an[g]);
        }
    }

    // activation selector: A-gate is sigm on half0 (k2=1), tanh on half1 (k2=2):
    // actA = fmaf(k2, sigm(k2*v)-1, 1)
    const float k2 = half ? 2.0f : 1.0f;

    // ---- zero state (read-buffer 0) ----
    if (half) {
        ((float*)&h0b[0][e][0])[j] = 0.0f;
        ((float*)&h1b[0][e][0])[j] = 0.0f;
    }
    float c0 = 0.0f, c1 = 0.0f;
    int p = 0;                          // read-buffer parity
    __syncthreads();

    const float* xrow = x + (size_t)elemc * T;

    for (int t = 0; t < T; ++t) {
        const float xv = xrow[t];
        const bool xp = xv > 0.0f;

        // ---- layer 0: a = x-term + b0 + w_hh0 . h0_{t-1} ----
        v2f aA = {fmaf(xv, xp ? ap[0] : an[0], bb0[0]), 0.0f};
        v2f aB = {fmaf(xv, xp ? ap[1] : an[1], bb0[1]), 0.0f};
        {
            const float4* hr = &h0b[p][e][0];          // broadcast reads
            #pragma unroll
            for (int c = 0; c < 4; ++c) {
                const float4 h4 = hr[c];
                const v2f lo = {h4.x, h4.y};
                const v2f hi = {h4.z, h4.w};
                aA = __builtin_elementwise_fma(wh0[0][2 * c], lo, aA);
                aA = __builtin_elementwise_fma(wh0[0][2 * c + 1], hi, aA);
                aB = __builtin_elementwise_fma(wh0[1][2 * c], lo, aB);
                aB = __builtin_elementwise_fma(wh0[1][2 * c + 1], hi, aB);
            }
        }
        {
            const float vA = aA[0] + aA[1];
            const float vB = aB[0] + aB[1];
            const float actA = fmaf(k2, sigm(k2 * vA) - 1.0f, 1.0f);
            const float actB = sigm(vB);
            const float xg = __shfl_xor(actA, 16, 64); // half0 <- tanh(g)
            c0 = fmaf(actB, c0, actA * xg);            // real c on half0
            const float tc = tanh_(c0);
            const float tx = __shfl_xor(tc, 16, 64);   // half1 <- tanh(c_real)
            if (half) ((float*)&h0b[p ^ 1][e][0])[j] = actB * tx;   // h0_t
        }
        __syncthreads();                               // h0_t visible

        // ---- layer 1: b1 + w_ih1 . h0_t + w_hh1 . h1_{t-1} ----
        v2f bA = {bb1[0], 0.0f};
        v2f bB = {bb1[1], 0.0f};
        {
            const float4* hn = &h0b[p ^ 1][e][0];      // h0_t
            const float4* ho = &h1b[p][e][0];          // h1_{t-1}
            #pragma unroll
            for (int c = 0; c < 4; ++c) {
                const float4 h4n = hn[c];
                const float4 h4o = ho[c];
                const v2f lon = {h4n.x, h4n.y};
                const v2f hin = {h4n.z, h4n.w};
                const v2f loo = {h4o.x, h4o.y};
                const v2f hio = {h4o.z, h4o.w};
                bA = __builtin_elementwise_fma(wi1[0][2 * c], lon, bA);
                bA = __builtin_elementwise_fma(wi1[0][2 * c + 1], hin, bA);
                bB = __builtin_elementwise_fma(wi1[1][2 * c], lon, bB);
                bB = __builtin_elementwise_fma(wi1[1][2 * c + 1], hin, bB);
                bA = __builtin_elementwise_fma(wh1[0][2 * c], loo, bA);
                bA = __builtin_elementwise_fma(wh1[0][2 * c + 1], hio, bA);
                bB = __builtin_elementwise_fma(wh1[1][2 * c], loo, bB);
                bB = __builtin_elementwise_fma(wh1[1][2 * c + 1], hio, bB);
            }
        }
        {
            const float vA = bA[0] + bA[1];
            const float vB = bB[0] + bB[1];
            const float actA = fmaf(k2, sigm(k2 * vA) - 1.0f, 1.0f);
            const float actB = sigm(vB);
            const float xg = __shfl_xor(actA, 16, 64);
            c1 = fmaf(actB, c1, actA * xg);
            const float tc = tanh_(c1);
            const float tx = __shfl_xor(tc, 16, 64);
            if (half) ((float*)&h1b[p ^ 1][e][0])[j] = actB * tx;   // h1_t
        }
        __syncthreads();                               // h1_t visible
        p ^= 1;
    }

    // ---- head: fc_h (16->8) + ReLU, fc_o (8->1) ----
    if (half == 0 && j < 8) {
        float acc = fc_h_b[j];
        #pragma unroll
        for (int c = 0; c < 4; ++c) {
            const float4 hv = h1b[p][e][c];
            acc = fmaf(fc_h_w[j * 16 + 4 * c + 0], hv.x, acc);
            acc = fmaf(fc_h_w[j * 16 + 4 * c + 1], hv.y, acc);
            acc = fmaf(fc_h_w[j * 16 + 4 * c + 2], hv.z, acc);
            acc = fmaf(fc_h_w[j * 16 + 4 * c + 3], hv.w, acc);
        }
        zb[e][j] = fmaxf(acc, 0.0f);
    }
    __syncthreads();
    if (sub == 0 && elem < B) {
        float acc = fc_o_b[0];
        #pragma unroll
        for (int r = 0; r < 8; ++r) acc = fmaf(fc_o_w[r], zb[e][r], acc);
        out[elem] = acc;
    }
}

// ---------------- guard kernel: general b_in != 0 path (R5 code, self-gating) ----------------

__device__ __forceinline__ float lstm_finish_g(v2f aA, v2f aB, float kA, float c1A,
                                               float c2A, float& cc) {
    const float hA = aA[0] + aA[1];
    const float hB = aB[0] + aB[1];
    const float actA =
        fmaf(c2A, __builtin_amdgcn_rcpf(1.0f + __builtin_amdgcn_exp2f(kA * hA)), c1A);
    const float actB = sigm(hB);
    const float xg = __shfl_xor(actA, 16, 64);
    cc = fmaf(actB, cc, actA * xg);
    const float t = tanh_(cc);
    const float tx = __shfl_xor(t, 16, 64);
    return actB * tx;
}

#define DOTRG(AA, AB, W, HP)                                          \
    _Pragma("unroll")                                                 \
    for (int c = 0; c < 4; ++c) {                                     \
        v2f hlo = {HP[c].x, HP[c].y};                                 \
        v2f hhi = {HP[c].z, HP[c].w};                                 \
        AA = __builtin_elementwise_fma(W[0][2 * c], hlo, AA);         \
        AA = __builtin_elementwise_fma(W[0][2 * c + 1], hhi, AA);     \
        AB = __builtin_elementwise_fma(W[1][2 * c], hlo, AB);         \
        AB = __builtin_elementwise_fma(W[1][2 * c + 1], hhi, AB);     \
    }

#define DOTLG(AA, AB, WROWA, WROWB, HP)                               \
    _Pragma("unroll")                                                 \
    for (int c = 0; c < 4; ++c) {                                     \
        float4 wa = ((const float4*)(WROWA))[c];                      \
        float4 wb = ((const float4*)(WROWB))[c];                      \
        v2f hlo = {HP[c].x, HP[c].y};                                 \
        v2f hhi = {HP[c].z, HP[c].w};                                 \
        AA = __builtin_elementwise_fma((v2f){wa.x, wa.y}, hlo, AA);   \
        AA = __builtin_elementwise_fma((v2f){wa.z, wa.w}, hhi, AA);   \
        AB = __builtin_elementwise_fma((v2f){wb.x, wb.y}, hlo, AB);   \
        AB = __builtin_elementwise_fma((v2f){wb.z, wb.w}, hhi, AB);   \
    }

__global__ __launch_bounds__(64, 2) void lstm_general(
    const float* __restrict__ x,
    const float* __restrict__ w_in, const float* __restrict__ b_in,
    const float* __restrict__ w_ih0, const float* __restrict__ w_hh0,
    const float* __restrict__ b_ih0, const float* __restrict__ b_hh0,
    const float* __restrict__ w_ih1, const float* __restrict__ w_hh1,
    const float* __restrict__ b_ih1, const float* __restrict__ b_hh1,
    const float* __restrict__ fc_h_w, const float* __restrict__ fc_h_b,
    const float* __restrict__ fc_o_w, const float* __restrict__ fc_o_b,
    float* __restrict__ out, int B, int T)
{
    bool bzero = true;
    #pragma unroll
    for (int k = 0; k < 16; ++k)
        if (b_in[k] != 0.0f) bzero = false;
    if (bzero) return;                  // fast kernel handles this case

    const int lane = threadIdx.x;
    const int e    = lane >> 5;
    const int sub  = lane & 31;
    const int j    = sub & 15;
    const int half = sub >> 4;
    const int elem  = blockIdx.x * 2 + e;
    const int elemc = elem < B ? elem : B - 1;
    const int rA = half * 32 + j;
    const int rB = rA + 16;

    __shared__ float  whh0s[64][20];
    __shared__ float4 h0g[2][2][4];
    __shared__ float4 h1g[2][2][4];
    __shared__ float  xib[2][16];

    {
        const int r = lane;
        const float4* src = (const float4*)(w_hh0 + r * 16);
        float4* dst = (float4*)&whh0s[r][0];
        #pragma unroll
        for (int c = 0; c < 4; ++c) dst[c] = src[c];
    }

    v2f wi1[2][8], wh1[2][8];
    float bb0[2], bb1[2];
    #pragma unroll
    for (int g = 0; g < 2; ++g) {
        const int row = g ? rB : rA;
        const float4* pi = (const float4*)(w_ih1 + row * 16);
        const float4* ph = (const float4*)(w_hh1 + row * 16);
        #pragma unroll
        for (int c = 0; c < 4; ++c) {
            float4 ti = pi[c], th = ph[c];
            wi1[g][2 * c]     = (v2f){ti.x, ti.y};
            wi1[g][2 * c + 1] = (v2f){ti.z, ti.w};
            wh1[g][2 * c]     = (v2f){th.x, th.y};
            wh1[g][2 * c + 1] = (v2f){th.z, th.w};
        }
        bb0[g] = b_ih0[row] + b_hh0[row];
        bb1[g] = b_ih1[row] + b_hh1[row];
    }

    const float kA  = half ? (2.0f * L2E) : (-L2E);
    const float c1A = half ? 1.0f : 0.0f;
    const float c2A = half ? -2.0f : 1.0f;

    if (half) {
        ((float*)&h0g[0][e][0])[j] = 0.0f;
        ((float*)&h1g[0][e][0])[j] = 0.0f;
    }
    float c0 = 0.0f, c1 = 0.0f;
    int p = 0;

    const float* xrow = x + (size_t)elemc * T;
    const float* wlA = &whh0s[rA][0];
    const float* wlB = &whh0s[rB][0];
    const float4* giA = (const float4*)(w_ih0 + rA * 16);
    const float4* giB = (const float4*)(w_ih0 + rB * 16);

    for (int t = 0; t < T; ++t) {
        const float xv = xrow[t];
        if (half == 0) xib[e][j] = fmaxf(fmaf(xv, w_in[j], b_in[j]), 0.0f);
        __syncthreads();
        float4 xi4[4];
        #pragma unroll
        for (int c = 0; c < 4; ++c) xi4[c] = *(const float4*)&xib[e][4 * c];
        v2f aA = {bb0[0], 0.0f};
        v2f aB = {bb0[1], 0.0f};
        DOTLG(aA, aB, giA, giB, xi4);
        float4 hp[4];
        #pragma unroll
        for (int c = 0; c < 4; ++c) hp[c] = h0g[p][e][c];
        DOTLG(aA, aB, wlA, wlB, hp);
        const float h0j = lstm_finish_g(aA, aB, kA, c1A, c2A, c0);
        if (half) ((float*)&h0g[p ^ 1][e][0])[j] = h0j;

        float4 hq[4];
        #pragma unroll
        for (int c = 0; c < 4; ++c) hq[c] = h1g[p][e][c];
        v2f bA = {bb1[0], 0.0f};
        v2f bB = {bb1[1], 0.0f};
        DOTRG(bA, bB, wh1, hq);
        __syncthreads();
        float4 hn[4];
        #pragma unroll
        for (int c = 0; c < 4; ++c) hn[c] = h0g[p ^ 1][e][c];
        DOTRG(bA, bB, wi1, hn);
        const float h1j = lstm_finish_g(bA, bB, kA, c1A, c2A, c1);
        if (half) ((float*)&h1g[p ^ 1][e][0])[j] = h1j;
        __syncthreads();
        p ^= 1;
    }

    if (half == 0 && j < 8) {
        float acc = fc_h_b[j];
        #pragma unroll
        for (int c = 0; c < 4; ++c) {
            float4 hv = h1g[p][e][c];
            acc = fmaf(fc_h_w[j * 16 + 4 * c + 0], hv.x, acc);
            acc = fmaf(fc_h_w[j * 16 + 4 * c + 1], hv.y, acc);
            acc = fmaf(fc_h_w[j * 16 + 4 * c + 2], hv.z, acc);
            acc = fmaf(fc_h_w[j * 16 + 4 * c + 3], hv.w, acc);
        }
        xib[e][j] = fmaxf(acc, 0.0f);
    }
    __syncthreads();
    if (sub == 0 && elem < B) {
        float acc = fc_o_b[0];
        #pragma unroll
        for (int r = 0; r < 8; ++r) acc = fmaf(fc_o_w[r], xib[e][r], acc);
        out[elem] = acc;
    }
}

extern "C" void kernel_launch(void* const* d_in, const int* in_sizes, int n_in,
                              void* d_out, int out_size, void* d_ws, size_t ws_size,
                              hipStream_t stream) {
    const float* x      = (const float*)d_in[0];
    const float* w_in   = (const float*)d_in[1];
    const float* b_in   = (const float*)d_in[2];
    const float* w_ih0  = (const float*)d_in[3];
    const float* w_hh0  = (const float*)d_in[4];
    const float* b_ih0  = (const float*)d_in[5];
    const float* b_hh0  = (const float*)d_in[6];
    const float* w_ih1  = (const float*)d_in[7];
    const float* w_hh1  = (const float*)d_in[8];
    const float* b_ih1  = (const float*)d_in[9];
    const float* b_hh1  = (const float*)d_in[10];
    const float* fc_h_w = (const float*)d_in[11];
    const float* fc_h_b = (const float*)d_in[12];
    const float* fc_o_w = (const float*)d_in[13];
    const float* fc_o_b = (const float*)d_in[14];

    const int B = out_size;                 // x is [B,T,1]
    const int T = in_sizes[0] / (B > 0 ? B : 1);
    const int grid = (B + EPW - 1) / EPW;

    hipLaunchKernelGGL(lstm_gsr, dim3(grid), dim3(64), 0, stream,
                       x, w_in, b_in, w_ih0, w_hh0, b_ih0, b_hh0,
                       w_ih1, w_hh1, b_ih1, b_hh1, fc_h_w, fc_h_b,
                       fc_o_w, fc_o_b, (float*)d_out, B, T);
    hipLaunchKernelGGL(lstm_general, dim3(grid), dim3(64), 0, stream,
                       x, w_in, b_in, w_ih0, w_hh0, b_ih0, b_hh0,
                       w_ih1, w_hh1, b_ih1, b_hh1, fc_h_w, fc_h_b,
                       fc_o_w, fc_o_b, (float*)d_out, B, T);
}

// Round 11
// 260.048 us; speedup vs baseline: 1.1163x; 1.1163x over previous
//
#include <hip/hip_runtime.h>
#include <math.h>

// LSTMLightweight on MI355X (R11: split-bf16 MFMA).
//   x[B,T,1] -> linear_in(1->16)+ReLU -> LSTM0(16) -> LSTM1(16) -> fc(16->8)+ReLU -> fc(8->1)
// R7-R10 lesson: the allocator refuses >~100 resident arch VGPRs of scalar
// loop-invariants; it AGPR-parks them at ~2 issue slots per value per use —
// every scalar-FMA structure pays ~2x. MFMA reads A/B operands from AGPRs
// DIRECTLY (cdna4_isa §10), so weights-as-MFMA-operands makes parking free.
// Structure: wave = 16 elements (MFMA cols). Per layer: G[64x16] = A·B,
// A = [W_ih|W_hh] (64x32) as 4 M-tiles of mfma_f32_16x16x32_bf16,
// B = [xi;h0] or [h0;h1] staged in LDS as pre-split bf16 hi/lo planes.
// Precision: 3 products (Ahi·Bhi + Ahi·Blo + Alo·Bhi), bias in C-init (f32);
// dropped terms ~2^-16 rel -> absmax ~1e-3 << 9.1e-3 threshold.
// Verified D-layout (m89/m91): col=lane&15 (element), row=(lane>>4)*4+reg ->
// lane (g,e) holds i,f,g,o of units j=4g+q across its 4 tile accs: combine is
// fully lane-local (c-state 8 regs, no shuffles). A/B frag layout assumed:
// row/col = lane&15, k = 8*(lane>>4)+i (CDNA blocked layout).
// xi computed generally (any b_in) — no guard kernel needed.

#define L2E 1.4426950408889634f
#define EPB 16        // elements per block (= MFMA N)
#define TCH 256       // x staging chunk length

typedef short bf16x8 __attribute__((ext_vector_type(8)));
typedef float f32x4  __attribute__((ext_vector_type(4)));

__device__ __forceinline__ float sigm(float v) {
    return __builtin_amdgcn_rcpf(1.0f + __builtin_amdgcn_exp2f(-L2E * v));
}
__device__ __forceinline__ float tanh_(float v) {
    // tanh(v) = 1 - 2/(exp(2v)+1); saturates correctly at +-inf
    return 1.0f - 2.0f * __builtin_amdgcn_rcpf(1.0f + __builtin_amdgcn_exp2f((2.0f * L2E) * v));
}
// bf16 split helpers (truncation split: hi = top 16 bits; lo = bf16(v - hi))
__device__ __forceinline__ float hif(float a) {
    return __uint_as_float(__float_as_uint(a) & 0xFFFF0000u);
}
__device__ __forceinline__ unsigned pk2hi(float a, float b) {   // pack 2 hi-bf16
    return (__float_as_uint(a) >> 16) | (__float_as_uint(b) & 0xFFFF0000u);
}
__device__ __forceinline__ unsigned pk2lo(float a, float b) {   // pack 2 lo-bf16
    const float ra = a - hif(a), rb = b - hif(b);
    return (__float_as_uint(ra) >> 16) | (__float_as_uint(rb) & 0xFFFF0000u);
}
__device__ __forceinline__ short bhi(float a) { return (short)(__float_as_uint(a) >> 16); }

__global__ __launch_bounds__(64) void lstm_mfma(
    const float* __restrict__ x,
    const float* __restrict__ w_in, const float* __restrict__ b_in,
    const float* __restrict__ w_ih0, const float* __restrict__ w_hh0,
    const float* __restrict__ b_ih0, const float* __restrict__ b_hh0,
    const float* __restrict__ w_ih1, const float* __restrict__ w_hh1,
    const float* __restrict__ b_ih1, const float* __restrict__ b_hh1,
    const float* __restrict__ fc_h_w, const float* __restrict__ fc_h_b,
    const float* __restrict__ fc_o_w, const float* __restrict__ fc_o_b,
    float* __restrict__ out, int B, int T)
{
    const int lane = threadIdx.x;        // 0..63
    const int e    = lane & 15;          // element column (and A-row within tile)
    const int g    = lane >> 4;          // k-group / D-row group
    const int base = blockIdx.x * EPB;

    // B-operand tables: 32 k-rows (+8 pad) per element, bf16 hi/lo planes.
    __shared__ unsigned short b0hi[EPB][40], b0lo[EPB][40];   // [xi(0-15); h0(16-31)]
    __shared__ unsigned short b1hi[EPB][40], b1lo[EPB][40];   // [h0new(0-15); h1(16-31)]
    __shared__ float xtab[EPB][TCH];
    __shared__ float htab[EPB][16];

    // ---- A-fragments (weights, split) + bias C-inits. Loop-invariant:
    // AGPR parking of these is FREE (MFMA reads AGPRs directly). ----
    bf16x8 a0hi[4], a0lo[4], a1hi[4], a1lo[4];
    f32x4  bias0[4], bias1[4];
    const int k0 = 8 * g;                // this lane's k-slice
    #pragma unroll
    for (int m = 0; m < 4; ++m) {
        const int r = 16 * m + e;        // A-frag row = lane&15 within tile m
        const float* s0 = (k0 < 16) ? (w_ih0 + r * 16 + k0) : (w_hh0 + r * 16 + (k0 - 16));
        const float* s1 = (k0 < 16) ? (w_ih1 + r * 16 + k0) : (w_hh1 + r * 16 + (k0 - 16));
        #pragma unroll
        for (int i = 0; i < 8; ++i) {
            const float w0 = s0[i], w1 = s1[i];
            a0hi[m][i] = bhi(w0);  a0lo[m][i] = bhi(w0 - hif(w0));
            a1hi[m][i] = bhi(w1);  a1lo[m][i] = bhi(w1 - hif(w1));
        }
        const int rd = 16 * m + 4 * g;   // D rows = (lane>>4)*4 + q
        #pragma unroll
        for (int q = 0; q < 4; ++q) {
            bias0[m][q] = b_ih0[rd + q] + b_hh0[rd + q];
            bias1[m][q] = b_ih1[rd + q] + b_hh1[rd + q];
        }
    }
    float winq[4], binq[4];
    #pragma unroll
    for (int q = 0; q < 4; ++q) { winq[q] = w_in[4 * g + q]; binq[q] = b_in[4 * g + q]; }

    // ---- zero h-state rows (h0 in b0[16:32], h1 in b1[16:32]) ----
    {
        uint2 z2; z2.x = 0u; z2.y = 0u;
        *(uint2*)&b0hi[e][16 + 4 * g] = z2;  *(uint2*)&b0lo[e][16 + 4 * g] = z2;
        *(uint2*)&b1hi[e][16 + 4 * g] = z2;  *(uint2*)&b1lo[e][16 + 4 * g] = z2;
    }
    float c0[4] = {0.f, 0.f, 0.f, 0.f};
    float c1[4] = {0.f, 0.f, 0.f, 0.f};
    float h1v[4] = {0.f, 0.f, 0.f, 0.f};

    for (int tb = 0; tb < T; tb += TCH) {
        const int tc = (T - tb) < TCH ? (T - tb) : TCH;
        __syncthreads();                          // xtab reads of prev chunk done
        if ((tc & 3) == 0) {                      // vector staging (T=256 path)
            const int nv = EPB * tc / 4;
            for (int idx = lane; idx < nv; idx += 64) {
                const int ee = (idx * 4) / tc, t0 = (idx * 4) % tc;
                int row = base + ee; if (row >= B) row = B - 1;
                *(float4*)&xtab[ee][t0] = *(const float4*)&x[(size_t)row * T + tb + t0];
            }
        } else {
            for (int idx = lane; idx < EPB * tc; idx += 64) {
                const int ee = idx / tc, t0 = idx % tc;
                int row = base + ee; if (row >= B) row = B - 1;
                xtab[ee][t0] = x[(size_t)row * T + tb + t0];
            }
        }
        __syncthreads();

        for (int tt = 0; tt < tc; ++tt) {
            // ---- xi_j = relu(x*w_in_j + b_in_j) for this lane's units j=4g+q ----
            const float xv = xtab[e][tt];
            float xq[4];
            #pragma unroll
            for (int q = 0; q < 4; ++q) xq[q] = fmaxf(fmaf(xv, winq[q], binq[q]), 0.0f);
            uint2 xh, xl;
            xh.x = pk2hi(xq[0], xq[1]); xh.y = pk2hi(xq[2], xq[3]);
            xl.x = pk2lo(xq[0], xq[1]); xl.y = pk2lo(xq[2], xq[3]);
            *(uint2*)&b0hi[e][4 * g] = xh;  *(uint2*)&b0lo[e][4 * g] = xl;
            __syncthreads();                      // barrier A: xi visible

            // ---- layer 0: G0 = [Wih0|Whh0]·[xi;h0] (+bias) ----
            const bf16x8 Bh0 = *(const bf16x8*)&b0hi[e][8 * g];
            const bf16x8 Bl0 = *(const bf16x8*)&b0lo[e][8 * g];
            f32x4 acc[4];
            #pragma unroll
            for (int m = 0; m < 4; ++m) {
                acc[m] = bias0[m];
                acc[m] = __builtin_amdgcn_mfma_f32_16x16x32_bf16(a0lo[m], Bh0, acc[m], 0, 0, 0);
                acc[m] = __builtin_amdgcn_mfma_f32_16x16x32_bf16(a0hi[m], Bl0, acc[m], 0, 0, 0);
                acc[m] = __builtin_amdgcn_mfma_f32_16x16x32_bf16(a0hi[m], Bh0, acc[m], 0, 0, 0);
            }
            float h0v[4];
            #pragma unroll
            for (int q = 0; q < 4; ++q) {         // i,f,g,o of unit 4g+q, elem e
                const float ig = sigm(acc[0][q]);
                const float fg = sigm(acc[1][q]);
                const float gv = tanh_(acc[2][q]);
                const float og = sigm(acc[3][q]);
                c0[q] = fmaf(fg, c0[q], ig * gv);
                h0v[q] = og * tanh_(c0[q]);
            }
            uint2 hh, hl;
            hh.x = pk2hi(h0v[0], h0v[1]); hh.y = pk2hi(h0v[2], h0v[3]);
            hl.x = pk2lo(h0v[0], h0v[1]); hl.y = pk2lo(h0v[2], h0v[3]);
            *(uint2*)&b1hi[e][4 * g] = hh;       *(uint2*)&b1lo[e][4 * g] = hl;        // h0_t for L1
            *(uint2*)&b0hi[e][16 + 4 * g] = hh;  *(uint2*)&b0lo[e][16 + 4 * g] = hl;   // h0_t for next step
            __syncthreads();                      // barrier B: h0_t visible

            // ---- layer 1: G1 = [Wih1|Whh1]·[h0_t;h1_{t-1}] (+bias) ----
            const bf16x8 Bh1 = *(const bf16x8*)&b1hi[e][8 * g];
            const bf16x8 Bl1 = *(const bf16x8*)&b1lo[e][8 * g];
            #pragma unroll
            for (int m = 0; m < 4; ++m) {
                acc[m] = bias1[m];
                acc[m] = __builtin_amdgcn_mfma_f32_16x16x32_bf16(a1lo[m], Bh1, acc[m], 0, 0, 0);
                acc[m] = __builtin_amdgcn_mfma_f32_16x16x32_bf16(a1hi[m], Bl1, acc[m], 0, 0, 0);
                acc[m] = __builtin_amdgcn_mfma_f32_16x16x32_bf16(a1hi[m], Bh1, acc[m], 0, 0, 0);
            }
            #pragma unroll
            for (int q = 0; q < 4; ++q) {
                const float ig = sigm(acc[0][q]);
                const float fg = sigm(acc[1][q]);
                const float gv = tanh_(acc[2][q]);
                const float og = sigm(acc[3][q]);
                c1[q] = fmaf(fg, c1[q], ig * gv);
                h1v[q] = og * tanh_(c1[q]);
            }
            uint2 jh, jl;
            jh.x = pk2hi(h1v[0], h1v[1]); jh.y = pk2hi(h1v[2], h1v[3]);
            jl.x = pk2lo(h1v[0], h1v[1]); jl.y = pk2lo(h1v[2], h1v[3]);
            *(uint2*)&b1hi[e][16 + 4 * g] = jh;  *(uint2*)&b1lo[e][16 + 4 * g] = jl;   // h1_t
            // next iteration's barrier A orders this write vs the next B1 read
        }
    }

    // ---- head: fc_h (16->8) + ReLU, fc_o (8->1) on final h1 (f32 from regs) ----
    *(float4*)&htab[e][4 * g] = make_float4(h1v[0], h1v[1], h1v[2], h1v[3]);
    __syncthreads();
    if (lane < EPB) {
        const int ee = lane;
        float hv[16];
        #pragma unroll
        for (int k = 0; k < 16; ++k) hv[k] = htab[ee][k];
        float z[8];
        #pragma unroll
        for (int p = 0; p < 8; ++p) {
            float acc = fc_h_b[p];
            #pragma unroll
            for (int k = 0; k < 16; ++k) acc = fmaf(fc_h_w[p * 16 + k], hv[k], acc);
            z[p] = fmaxf(acc, 0.0f);
        }
        float o = fc_o_b[0];
        #pragma unroll
        for (int p = 0; p < 8; ++p) o = fmaf(fc_o_w[p], z[p], o);
        if (base + ee < B) out[base + ee] = o;
    }
}

extern "C" void kernel_launch(void* const* d_in, const int* in_sizes, int n_in,
                              void* d_out, int out_size, void* d_ws, size_t ws_size,
                              hipStream_t stream) {
    const float* x      = (const float*)d_in[0];
    const float* w_in   = (const float*)d_in[1];
    const float* b_in   = (const float*)d_in[2];
    const float* w_ih0  = (const float*)d_in[3];
    const float* w_hh0  = (const float*)d_in[4];
    const float* b_ih0  = (const float*)d_in[5];
    const float* b_hh0  = (const float*)d_in[6];
    const float* w_ih1  = (const float*)d_in[7];
    const float* w_hh1  = (const float*)d_in[8];
    const float* b_ih1  = (const float*)d_in[9];
    const float* b_hh1  = (const float*)d_in[10];
    const float* fc_h_w = (const float*)d_in[11];
    const float* fc_h_b = (const float*)d_in[12];
    const float* fc_o_w = (const float*)d_in[13];
    const float* fc_o_b = (const float*)d_in[14];

    const int B = out_size;                 // x is [B,T,1]
    const int T = in_sizes[0] / (B > 0 ? B : 1);
    const int grid = (B + EPB - 1) / EPB;   // 512 blocks at B=8192

    hipLaunchKernelGGL(lstm_mfma, dim3(grid), dim3(64), 0, stream,
                       x, w_in, b_in, w_ih0, w_hh0, b_ih0, b_hh0,
                       w_ih1, w_hh1, b_ih1, b_hh1, fc_h_w, fc_h_b,
                       fc_o_w, fc_o_b, (float*)d_out, B, T);
}

// Round 12
// 223.689 us; speedup vs baseline: 1.2977x; 1.1625x over previous
//
#include <hip/hip_runtime.h>
#include <math.h>

// LSTMLightweight on MI355X (R12: register-local split-bf16 MFMA, zero-LDS loop).
//   x[B,T,1] -> linear_in(1->16)+ReLU -> LSTM0(16) -> LSTM1(16) -> fc(16->8)+ReLU -> fc(8->1)
// R11 lesson: MFMA structure correct (absmax 2e-3, MfmaUtil 7.4%) but the
// LDS+barrier round-trip for the B-operand dominated at 0.5 waves/SIMD
// (2400 cyc/step, 10.4M bank conflicts).
// R12 trick: permute A's K-columns so the B-fragment becomes LANE-LOCAL.
//   K-order: k = 8g+i  ->  W_ih[.][4g+i] (i<4) | W_hh[.][4g+i-4] (i>=4).
//   B-frag of lane (g,e) = [xi_e[4g..4g+3]; h_e[4g..4g+3]] — exactly the units
//   that lane computes itself (D-layout row = 4*(lane>>4)+reg, col = lane&15,
//   verified in R11). The MFMA's internal cross-lane k-reduction does all the
//   h-mixing -> NO LDS, NO barriers, NO shuffles anywhere in the timestep.
// Weights are MFMA A-operands (AGPR-parking is free — the R7-R10 scalar-FMA
// demotion tax doesn't apply). Split-bf16 3-product scheme as R11.
// xi computed natively from w_in/b_in (any bias) — no guard kernel.

#define L2E 1.4426950408889634f
#define EPB 16        // elements per wave (= MFMA N)

typedef short bf16x8 __attribute__((ext_vector_type(8)));
typedef float f32x4  __attribute__((ext_vector_type(4)));
typedef int   i32x4  __attribute__((ext_vector_type(4)));

__device__ __forceinline__ float sigm(float v) {
    return __builtin_amdgcn_rcpf(1.0f + __builtin_amdgcn_exp2f(-L2E * v));
}
__device__ __forceinline__ float tanh_(float v) {
    // tanh(v) = 1 - 2/(exp(2v)+1); saturates correctly at +-inf
    return 1.0f - 2.0f * __builtin_amdgcn_rcpf(1.0f + __builtin_amdgcn_exp2f((2.0f * L2E) * v));
}
// bf16 split helpers (truncation split: hi = top 16 bits; lo = bf16(v - hi))
__device__ __forceinline__ float hif(float a) {
    return __uint_as_float(__float_as_uint(a) & 0xFFFF0000u);
}
__device__ __forceinline__ unsigned pk2hi(float a, float b) {   // pack 2 hi-bf16
    return (__float_as_uint(a) >> 16) | (__float_as_uint(b) & 0xFFFF0000u);
}
__device__ __forceinline__ unsigned pk2lo(float a, float b) {   // pack 2 lo-bf16
    const float ra = a - hif(a), rb = b - hif(b);
    return (__float_as_uint(ra) >> 16) | (__float_as_uint(rb) & 0xFFFF0000u);
}
__device__ __forceinline__ short bhi(float a) { return (short)(__float_as_uint(a) >> 16); }
__device__ __forceinline__ bf16x8 mkfrag(unsigned w0, unsigned w1, unsigned w2, unsigned w3) {
    i32x4 t = {(int)w0, (int)w1, (int)w2, (int)w3};
    return __builtin_bit_cast(bf16x8, t);
}

__global__ __launch_bounds__(64) void lstm_mfma_reg(
    const float* __restrict__ x,
    const float* __restrict__ w_in, const float* __restrict__ b_in,
    const float* __restrict__ w_ih0, const float* __restrict__ w_hh0,
    const float* __restrict__ b_ih0, const float* __restrict__ b_hh0,
    const float* __restrict__ w_ih1, const float* __restrict__ w_hh1,
    const float* __restrict__ b_ih1, const float* __restrict__ b_hh1,
    const float* __restrict__ fc_h_w, const float* __restrict__ fc_h_b,
    const float* __restrict__ fc_o_w, const float* __restrict__ fc_o_b,
    float* __restrict__ out, int B, int T)
{
    const int lane = threadIdx.x;        // 0..63
    const int e    = lane & 15;          // element column (= A row within tile)
    const int g    = lane >> 4;          // k-group / D-row group
    const int base = blockIdx.x * EPB;
    int rowe = base + e; if (rowe >= B) rowe = B - 1;

    __shared__ float htab[EPB][16];      // head exchange only (end of kernel)

    // ---- A-fragments with PERMUTED K: k=8g+i -> W_ih[.][4g+i] | W_hh[.][4g+i-4].
    // These are MFMA operands: AGPR residency is free. ----
    bf16x8 a0hi[4], a0lo[4], a1hi[4], a1lo[4];
    f32x4  bias0[4], bias1[4];
    #pragma unroll
    for (int m = 0; m < 4; ++m) {
        const int r = 16 * m + e;        // A row = lane&15 within tile m
        #pragma unroll
        for (int i = 0; i < 8; ++i) {
            const float w0 = (i < 4) ? w_ih0[r * 16 + 4 * g + i]
                                     : w_hh0[r * 16 + 4 * g + (i - 4)];
            const float w1 = (i < 4) ? w_ih1[r * 16 + 4 * g + i]
                                     : w_hh1[r * 16 + 4 * g + (i - 4)];
            a0hi[m][i] = bhi(w0);  a0lo[m][i] = bhi(w0 - hif(w0));
            a1hi[m][i] = bhi(w1);  a1lo[m][i] = bhi(w1 - hif(w1));
        }
        const int rd = 16 * m + 4 * g;   // D rows of this lane: rd+q
        #pragma unroll
        for (int q = 0; q < 4; ++q) {
            bias0[m][q] = b_ih0[rd + q] + b_hh0[rd + q];
            bias1[m][q] = b_ih1[rd + q] + b_hh1[rd + q];
        }
    }
    float winq[4], binq[4];
    #pragma unroll
    for (int q = 0; q < 4; ++q) { winq[q] = w_in[4 * g + q]; binq[q] = b_in[4 * g + q]; }

    // ---- state: c in f32 regs; h as packed bf16 hi/lo plane words ----
    float c0[4] = {0.f, 0.f, 0.f, 0.f};
    float c1[4] = {0.f, 0.f, 0.f, 0.f};
    float h1v[4] = {0.f, 0.f, 0.f, 0.f};
    unsigned h0h0 = 0u, h0h1 = 0u, h0l0 = 0u, h0l1 = 0u;   // h0_{t-1} packs
    unsigned h1h0 = 0u, h1h1 = 0u, h1l0 = 0u, h1l1 = 0u;   // h1_{t-1} packs

    const float* xrow = x + (size_t)rowe * T;
    float xv = xrow[0];

    for (int t = 0; t < T; ++t) {
        const int tn = (t + 1 < T) ? (t + 1) : (T - 1);
        const float xn = xrow[tn];                      // prefetch next step

        // ---- xi_j = relu(x*w_in_j + b_in_j), j = 4g+q (this lane's units) ----
        float xq[4];
        #pragma unroll
        for (int q = 0; q < 4; ++q) xq[q] = fmaxf(fmaf(xv, winq[q], binq[q]), 0.0f);
        const unsigned xh0 = pk2hi(xq[0], xq[1]), xh1 = pk2hi(xq[2], xq[3]);
        const unsigned xl0 = pk2lo(xq[0], xq[1]), xl1 = pk2lo(xq[2], xq[3]);

        // ---- layer 0: B0 = [xi(local); h0_{t-1}(local)] — register concat ----
        const bf16x8 B0h = mkfrag(xh0, xh1, h0h0, h0h1);
        const bf16x8 B0l = mkfrag(xl0, xl1, h0l0, h0l1);
        f32x4 acc[4];
        #pragma unroll
        for (int m = 0; m < 4; ++m) {
            acc[m] = bias0[m];
            acc[m] = __builtin_amdgcn_mfma_f32_16x16x32_bf16(a0lo[m], B0h, acc[m], 0, 0, 0);
            acc[m] = __builtin_amdgcn_mfma_f32_16x16x32_bf16(a0hi[m], B0l, acc[m], 0, 0, 0);
            acc[m] = __builtin_amdgcn_mfma_f32_16x16x32_bf16(a0hi[m], B0h, acc[m], 0, 0, 0);
        }
        float h0v[4];
        #pragma unroll
        for (int q = 0; q < 4; ++q) {    // i,f,g,o of unit 4g+q, element e
            const float ig = sigm(acc[0][q]);
            const float fg = sigm(acc[1][q]);
            const float gv = tanh_(acc[2][q]);
            const float og = sigm(acc[3][q]);
            c0[q] = fmaf(fg, c0[q], ig * gv);
            h0v[q] = og * tanh_(c0[q]);
        }
        const unsigned nh0 = pk2hi(h0v[0], h0v[1]), nh1 = pk2hi(h0v[2], h0v[3]);
        const unsigned nl0 = pk2lo(h0v[0], h0v[1]), nl1 = pk2lo(h0v[2], h0v[3]);

        // ---- layer 1: B1 = [h0_t(local); h1_{t-1}(local)] ----
        const bf16x8 B1h = mkfrag(nh0, nh1, h1h0, h1h1);
        const bf16x8 B1l = mkfrag(nl0, nl1, h1l0, h1l1);
        #pragma unroll
        for (int m = 0; m < 4; ++m) {
            acc[m] = bias1[m];
            acc[m] = __builtin_amdgcn_mfma_f32_16x16x32_bf16(a1lo[m], B1h, acc[m], 0, 0, 0);
            acc[m] = __builtin_amdgcn_mfma_f32_16x16x32_bf16(a1hi[m], B1l, acc[m], 0, 0, 0);
            acc[m] = __builtin_amdgcn_mfma_f32_16x16x32_bf16(a1hi[m], B1h, acc[m], 0, 0, 0);
        }
        #pragma unroll
        for (int q = 0; q < 4; ++q) {
            const float ig = sigm(acc[0][q]);
            const float fg = sigm(acc[1][q]);
            const float gv = tanh_(acc[2][q]);
            const float og = sigm(acc[3][q]);
            c1[q] = fmaf(fg, c1[q], ig * gv);
            h1v[q] = og * tanh_(c1[q]);
        }
        h1h0 = pk2hi(h1v[0], h1v[1]); h1h1 = pk2hi(h1v[2], h1v[3]);
        h1l0 = pk2lo(h1v[0], h1v[1]); h1l1 = pk2lo(h1v[2], h1v[3]);
        h0h0 = nh0; h0h1 = nh1; h0l0 = nl0; h0l1 = nl1;
        xv = xn;
    }

    // ---- head: fc_h (16->8) + ReLU, fc_o (8->1) on final h1 (f32 from regs) ----
    *(float4*)&htab[e][4 * g] = make_float4(h1v[0], h1v[1], h1v[2], h1v[3]);
    __syncthreads();
    if (lane < EPB) {
        const int ee = lane;
        float hv[16];
        #pragma unroll
        for (int k = 0; k < 16; ++k) hv[k] = htab[ee][k];
        float z[8];
        #pragma unroll
        for (int p = 0; p < 8; ++p) {
            float acc = fc_h_b[p];
            #pragma unroll
            for (int k = 0; k < 16; ++k) acc = fmaf(fc_h_w[p * 16 + k], hv[k], acc);
            z[p] = fmaxf(acc, 0.0f);
        }
        float o = fc_o_b[0];
        #pragma unroll
        for (int p = 0; p < 8; ++p) o = fmaf(fc_o_w[p], z[p], o);
        if (base + ee < B) out[base + ee] = o;
    }
}

extern "C" void kernel_launch(void* const* d_in, const int* in_sizes, int n_in,
                              void* d_out, int out_size, void* d_ws, size_t ws_size,
                              hipStream_t stream) {
    const float* x      = (const float*)d_in[0];
    const float* w_in   = (const float*)d_in[1];
    const float* b_in   = (const float*)d_in[2];
    const float* w_ih0  = (const float*)d_in[3];
    const float* w_hh0  = (const float*)d_in[4];
    const float* b_ih0  = (const float*)d_in[5];
    const float* b_hh0  = (const float*)d_in[6];
    const float* w_ih1  = (const float*)d_in[7];
    const float* w_hh1  = (const float*)d_in[8];
    const float* b_ih1  = (const float*)d_in[9];
    const float* b_hh1  = (const float*)d_in[10];
    const float* fc_h_w = (const float*)d_in[11];
    const float* fc_h_b = (const float*)d_in[12];
    const float* fc_o_w = (const float*)d_in[13];
    const float* fc_o_b = (const float*)d_in[14];

    const int B = out_size;                 // x is [B,T,1]
    const int T = in_sizes[0] / (B > 0 ? B : 1);
    const int grid = (B + EPB - 1) / EPB;   // 512 blocks at B=8192

    hipLaunchKernelGGL(lstm_mfma_reg, dim3(grid), dim3(64), 0, stream,
                       x, w_in, b_in, w_ih0, w_hh0, b_ih0, b_hh0,
                       w_ih1, w_hh1, b_ih1, b_hh1, fc_h_w, fc_h_b,
                       fc_o_w, fc_o_b, (float*)d_out, B, T);
}

// Round 13
// 222.454 us; speedup vs baseline: 1.3049x; 1.0056x over previous
//
#include <hip/hip_runtime.h>
#include <math.h>

// LSTMLightweight on MI355X (R13: layer-pipelined split-bf16 MFMA).
//   x[B,T,1] -> linear_in(1->16)+ReLU -> LSTM0(16) -> LSTM1(16) -> fc(16->8)+ReLU -> fc(8->1)
// R12 lesson: zero-LDS MFMA loop correct (223us, absmax 2e-3) but wave count is
// capped at B/16=512 = 0.5 waves/SIMD; the ~80 quarter-rate transcendental
// instrs/step (~640 cyc issue) plus the serial chain run with nothing to hide
// them (1830 cyc/step measured).
// R13: split layers across TWO waves per block in a 1-step-skewed pipeline:
//   wave0 = layer0 at step t; wave1 = layer1 at step t-1 (concurrent).
//   -> 1024 waves (every SIMD busy) and half the chain per wave.
// Handshake: wave0 writes h0_t packs to LDS buf[t&1]; wave1 reads buf[(t-1)&1]
// — disjoint slots => ONE __syncthreads() per step orders everything.
// Math identical to R12: K-permuted A so B-frags are lane-local
// (k=8g+i -> W_ih[.][4g+i] | W_hh[.][4g+i-4]; D row=4*(lane>>4)+q, col=lane&15
// — verified R11/R12), split-bf16 3-product MFMA, bias in C-init.

#define L2E 1.4426950408889634f
#define EPB 16        // elements per block (= MFMA N)

typedef short bf16x8 __attribute__((ext_vector_type(8)));
typedef float f32x4  __attribute__((ext_vector_type(4)));
typedef int   i32x4  __attribute__((ext_vector_type(4)));

__device__ __forceinline__ float sigm(float v) {
    return __builtin_amdgcn_rcpf(1.0f + __builtin_amdgcn_exp2f(-L2E * v));
}
__device__ __forceinline__ float tanh_(float v) {
    // tanh(v) = 1 - 2/(exp(2v)+1); saturates correctly at +-inf
    return 1.0f - 2.0f * __builtin_amdgcn_rcpf(1.0f + __builtin_amdgcn_exp2f((2.0f * L2E) * v));
}
// bf16 split helpers (truncation split: hi = top 16 bits; lo = bf16(v - hi))
__device__ __forceinline__ float hif(float a) {
    return __uint_as_float(__float_as_uint(a) & 0xFFFF0000u);
}
__device__ __forceinline__ unsigned pk2hi(float a, float b) {
    return (__float_as_uint(a) >> 16) | (__float_as_uint(b) & 0xFFFF0000u);
}
__device__ __forceinline__ unsigned pk2lo(float a, float b) {
    const float ra = a - hif(a), rb = b - hif(b);
    return (__float_as_uint(ra) >> 16) | (__float_as_uint(rb) & 0xFFFF0000u);
}
__device__ __forceinline__ short bhi(float a) { return (short)(__float_as_uint(a) >> 16); }
__device__ __forceinline__ bf16x8 mkfrag(unsigned w0, unsigned w1, unsigned w2, unsigned w3) {
    i32x4 t = {(int)w0, (int)w1, (int)w2, (int)w3};
    return __builtin_bit_cast(bf16x8, t);
}

__global__ __launch_bounds__(128) void lstm_pipe(
    const float* __restrict__ x,
    const float* __restrict__ w_in, const float* __restrict__ b_in,
    const float* __restrict__ w_ih0, const float* __restrict__ w_hh0,
    const float* __restrict__ b_ih0, const float* __restrict__ b_hh0,
    const float* __restrict__ w_ih1, const float* __restrict__ w_hh1,
    const float* __restrict__ b_ih1, const float* __restrict__ b_hh1,
    const float* __restrict__ fc_h_w, const float* __restrict__ fc_h_b,
    const float* __restrict__ fc_o_w, const float* __restrict__ fc_o_b,
    float* __restrict__ out, int B, int T)
{
    const int tid  = threadIdx.x;
    const int wid  = tid >> 6;           // 0: layer0 producer, 1: layer1 consumer
    const int lane = tid & 63;
    const int e    = lane & 15;          // element column
    const int g    = lane >> 4;          // k-group / D-row group
    const int base = blockIdx.x * EPB;
    int rowe = base + e; if (rowe >= B) rowe = B - 1;

    // h0 handoff: [slot][g][e][4 words: hi0,hi1,lo0,lo1]; double-buffered.
    __shared__ unsigned h0buf[2][4][EPB][4];
    __shared__ float htab[EPB][16];

    // ---- per-wave A-fragments (own layer only), K-permuted, split bf16 ----
    const float* wih = wid ? w_ih1 : w_ih0;
    const float* whh = wid ? w_hh1 : w_hh0;
    const float* bih = wid ? b_ih1 : b_ih0;
    const float* bhh = wid ? b_hh1 : b_hh0;
    bf16x8 ahi[4], alo[4];
    f32x4  bias[4];
    #pragma unroll
    for (int m = 0; m < 4; ++m) {
        const int r = 16 * m + e;        // A row = lane&15 within tile m
        #pragma unroll
        for (int i = 0; i < 8; ++i) {
            const float w = (i < 4) ? wih[r * 16 + 4 * g + i]
                                    : whh[r * 16 + 4 * g + (i - 4)];
            ahi[m][i] = bhi(w);  alo[m][i] = bhi(w - hif(w));
        }
        const int rd = 16 * m + 4 * g;   // D rows of this lane: rd+q
        #pragma unroll
        for (int q = 0; q < 4; ++q) bias[m][q] = bih[rd + q] + bhh[rd + q];
    }
    float winq[4], binq[4];
    #pragma unroll
    for (int q = 0; q < 4; ++q) { winq[q] = w_in[4 * g + q]; binq[q] = b_in[4 * g + q]; }

    // ---- per-wave recurrent state (wave0: h0/c0; wave1: h1/c1) ----
    float cc[4]  = {0.f, 0.f, 0.f, 0.f};
    float hv[4]  = {0.f, 0.f, 0.f, 0.f};
    unsigned hh0 = 0u, hh1 = 0u, hl0 = 0u, hl1 = 0u;   // own h_{t-1} packs

    const float* xrow = x + (size_t)rowe * T;
    float xv = xrow[0];

    for (int it = 0; it <= T; ++it) {
        if (wid == 0) {
            if (it < T) {
                const int tn = (it + 1 < T) ? (it + 1) : (T - 1);
                const float xn = xrow[tn];                   // prefetch
                // xi_j = relu(x*w_in_j + b_in_j), j = 4g+q
                float xq[4];
                #pragma unroll
                for (int q = 0; q < 4; ++q)
                    xq[q] = fmaxf(fmaf(xv, winq[q], binq[q]), 0.0f);
                const bf16x8 Bh = mkfrag(pk2hi(xq[0], xq[1]), pk2hi(xq[2], xq[3]), hh0, hh1);
                const bf16x8 Bl = mkfrag(pk2lo(xq[0], xq[1]), pk2lo(xq[2], xq[3]), hl0, hl1);
                f32x4 acc[4];
                #pragma unroll
                for (int m = 0; m < 4; ++m) {
                    acc[m] = bias[m];
                    acc[m] = __builtin_amdgcn_mfma_f32_16x16x32_bf16(alo[m], Bh, acc[m], 0, 0, 0);
                    acc[m] = __builtin_amdgcn_mfma_f32_16x16x32_bf16(ahi[m], Bl, acc[m], 0, 0, 0);
                    acc[m] = __builtin_amdgcn_mfma_f32_16x16x32_bf16(ahi[m], Bh, acc[m], 0, 0, 0);
                }
                #pragma unroll
                for (int q = 0; q < 4; ++q) {
                    const float ig = sigm(acc[0][q]);
                    const float fg = sigm(acc[1][q]);
                    const float gv = tanh_(acc[2][q]);
                    const float og = sigm(acc[3][q]);
                    cc[q] = fmaf(fg, cc[q], ig * gv);
                    hv[q] = og * tanh_(cc[q]);
                }
                hh0 = pk2hi(hv[0], hv[1]); hh1 = pk2hi(hv[2], hv[3]);
                hl0 = pk2lo(hv[0], hv[1]); hl1 = pk2lo(hv[2], hv[3]);
                uint4 w4; w4.x = hh0; w4.y = hh1; w4.z = hl0; w4.w = hl1;
                *(uint4*)&h0buf[it & 1][g][e][0] = w4;       // publish h0_t
                xv = xn;
            }
        } else {
            if (it > 0) {
                const int t = it - 1;
                const uint4 w4 = *(const uint4*)&h0buf[t & 1][g][e][0];   // h0_t
                const bf16x8 Bh = mkfrag(w4.x, w4.y, hh0, hh1);
                const bf16x8 Bl = mkfrag(w4.z, w4.w, hl0, hl1);
                f32x4 acc[4];
                #pragma unroll
                for (int m = 0; m < 4; ++m) {
                    acc[m] = bias[m];
                    acc[m] = __builtin_amdgcn_mfma_f32_16x16x32_bf16(alo[m], Bh, acc[m], 0, 0, 0);
                    acc[m] = __builtin_amdgcn_mfma_f32_16x16x32_bf16(ahi[m], Bl, acc[m], 0, 0, 0);
                    acc[m] = __builtin_amdgcn_mfma_f32_16x16x32_bf16(ahi[m], Bh, acc[m], 0, 0, 0);
                }
                #pragma unroll
                for (int q = 0; q < 4; ++q) {
                    const float ig = sigm(acc[0][q]);
                    const float fg = sigm(acc[1][q]);
                    const float gv = tanh_(acc[2][q]);
                    const float og = sigm(acc[3][q]);
                    cc[q] = fmaf(fg, cc[q], ig * gv);
                    hv[q] = og * tanh_(cc[q]);
                }
                hh0 = pk2hi(hv[0], hv[1]); hh1 = pk2hi(hv[2], hv[3]);
                hl0 = pk2lo(hv[0], hv[1]); hl1 = pk2lo(hv[2], hv[3]);
            }
        }
        __syncthreads();   // orders wave0's buf[it&1] write vs wave1's next read
    }

    // ---- head: fc_h (16->8) + ReLU, fc_o (8->1) on wave1's final h1 ----
    if (wid == 1) *(float4*)&htab[e][4 * g] = make_float4(hv[0], hv[1], hv[2], hv[3]);
    __syncthreads();
    if (tid < EPB) {
        const int ee = tid;
        float hvv[16];
        #pragma unroll
        for (int k = 0; k < 16; ++k) hvv[k] = htab[ee][k];
        float z[8];
        #pragma unroll
        for (int p = 0; p < 8; ++p) {
            float acc = fc_h_b[p];
            #pragma unroll
            for (int k = 0; k < 16; ++k) acc = fmaf(fc_h_w[p * 16 + k], hvv[k], acc);
            z[p] = fmaxf(acc, 0.0f);
        }
        float o = fc_o_b[0];
        #pragma unroll
        for (int p = 0; p < 8; ++p) o = fmaf(fc_o_w[p], z[p], o);
        if (base + ee < B) out[base + ee] = o;
    }
}

extern "C" void kernel_launch(void* const* d_in, const int* in_sizes, int n_in,
                              void* d_out, int out_size, void* d_ws, size_t ws_size,
                              hipStream_t stream) {
    const float* x      = (const float*)d_in[0];
    const float* w_in   = (const float*)d_in[1];
    const float* b_in   = (const float*)d_in[2];
    const float* w_ih0  = (const float*)d_in[3];
    const float* w_hh0  = (const float*)d_in[4];
    const float* b_ih0  = (const float*)d_in[5];
    const float* b_hh0  = (const float*)d_in[6];
    const float* w_ih1  = (const float*)d_in[7];
    const float* w_hh1  = (const float*)d_in[8];
    const float* b_ih1  = (const float*)d_in[9];
    const float* b_hh1  = (const float*)d_in[10];
    const float* fc_h_w = (const float*)d_in[11];
    const float* fc_h_b = (const float*)d_in[12];
    const float* fc_o_w = (const float*)d_in[13];
    const float* fc_o_b = (const float*)d_in[14];

    const int B = out_size;                 // x is [B,T,1]
    const int T = in_sizes[0] / (B > 0 ? B : 1);
    const int grid = (B + EPB - 1) / EPB;   // 512 blocks at B=8192

    hipLaunchKernelGGL(lstm_pipe, dim3(grid), dim3(128), 0, stream,
                       x, w_in, b_in, w_ih0, w_hh0, b_ih0, b_hh0,
                       w_ih1, w_hh1, b_ih1, b_hh1, fc_h_w, fc_h_b,
                       fc_o_w, fc_o_b, (float*)d_out, B, T);
}

// Round 14
// 202.169 us; speedup vs baseline: 1.4359x; 1.1003x over previous
//
#include <hip/hip_runtime.h>
#include <math.h>

// LSTMLightweight on MI355X (R14: intra-wave layer software-pipeline).
//   x[B,T,1] -> linear_in(1->16)+ReLU -> LSTM0(16) -> LSTM1(16) -> fc(16->8)+ReLU -> fc(8->1)
// R12/R13 lesson: latency-bound at ~2080 cyc/step (VALU 34-37%, Mfma 8.8%,
// no spill/conflict): serial MFMA->acc->transcendental->pack chain, L0 then L1
// executed back-to-back in program order. Wave-level pipelining (R13) was null
// (barrier lockstep). R14 pipelines WITHIN the wave: iteration t computes
//   L1(t)  from {h0(t), h1(t-1)}   and   L0(t+1) from {x(t+1), h0(t)}
// — mutually independent -> one straight-line body; the compiler's list
// scheduler interleaves the two chains so each chain's stalls are filled by
// the other's issue. No barriers, no LDS in the loop.
// Math identical to R12 (verified absmax 2e-3): K-permuted A-frags so B is
// lane-local (k=8g+i -> W_ih[.][4g+i] | W_hh[.][4g+i-4]; D row=4*(lane>>4)+q,
// col=lane&15), split-bf16 3-product MFMA, bias in C-init.

#define L2E 1.4426950408889634f
#define EPB 16        // elements per wave (= MFMA N)

typedef short bf16x8 __attribute__((ext_vector_type(8)));
typedef float f32x4  __attribute__((ext_vector_type(4)));
typedef int   i32x4  __attribute__((ext_vector_type(4)));

__device__ __forceinline__ float sigm(float v) {
    return __builtin_amdgcn_rcpf(1.0f + __builtin_amdgcn_exp2f(-L2E * v));
}
__device__ __forceinline__ float tanh_(float v) {
    // tanh(v) = 1 - 2/(exp(2v)+1); saturates correctly at +-inf
    return 1.0f - 2.0f * __builtin_amdgcn_rcpf(1.0f + __builtin_amdgcn_exp2f((2.0f * L2E) * v));
}
// bf16 split helpers (truncation split: hi = top 16 bits; lo = bf16(v - hi))
__device__ __forceinline__ float hif(float a) {
    return __uint_as_float(__float_as_uint(a) & 0xFFFF0000u);
}
__device__ __forceinline__ unsigned pk2hi(float a, float b) {
    return (__float_as_uint(a) >> 16) | (__float_as_uint(b) & 0xFFFF0000u);
}
__device__ __forceinline__ unsigned pk2lo(float a, float b) {
    const float ra = a - hif(a), rb = b - hif(b);
    return (__float_as_uint(ra) >> 16) | (__float_as_uint(rb) & 0xFFFF0000u);
}
__device__ __forceinline__ short bhi(float a) { return (short)(__float_as_uint(a) >> 16); }
__device__ __forceinline__ bf16x8 mkfrag(unsigned w0, unsigned w1, unsigned w2, unsigned w3) {
    i32x4 t = {(int)w0, (int)w1, (int)w2, (int)w3};
    return __builtin_bit_cast(bf16x8, t);
}

// one layer's gate MFMAs: acc[m] = bias[m] + split-bf16(A)·B
#define GATES(ACC, AHI, ALO, BIAS, BH, BL)                                           \
    _Pragma("unroll")                                                                \
    for (int m = 0; m < 4; ++m) {                                                    \
        ACC[m] = BIAS[m];                                                            \
        ACC[m] = __builtin_amdgcn_mfma_f32_16x16x32_bf16(ALO[m], BH, ACC[m], 0, 0, 0); \
        ACC[m] = __builtin_amdgcn_mfma_f32_16x16x32_bf16(AHI[m], BL, ACC[m], 0, 0, 0); \
        ACC[m] = __builtin_amdgcn_mfma_f32_16x16x32_bf16(AHI[m], BH, ACC[m], 0, 0, 0); \
    }

// combine: i,f,g,o -> c,h (per q); writes HV[4] and updates CC[4]
#define COMBINE(ACC, CC, HV)                                                         \
    _Pragma("unroll")                                                                \
    for (int q = 0; q < 4; ++q) {                                                    \
        const float ig_ = sigm(ACC[0][q]);                                           \
        const float fg_ = sigm(ACC[1][q]);                                           \
        const float gv_ = tanh_(ACC[2][q]);                                          \
        const float og_ = sigm(ACC[3][q]);                                           \
        CC[q] = fmaf(fg_, CC[q], ig_ * gv_);                                         \
        HV[q] = og_ * tanh_(CC[q]);                                                  \
    }

__global__ __launch_bounds__(64) void lstm_swp(
    const float* __restrict__ x,
    const float* __restrict__ w_in, const float* __restrict__ b_in,
    const float* __restrict__ w_ih0, const float* __restrict__ w_hh0,
    const float* __restrict__ b_ih0, const float* __restrict__ b_hh0,
    const float* __restrict__ w_ih1, const float* __restrict__ w_hh1,
    const float* __restrict__ b_ih1, const float* __restrict__ b_hh1,
    const float* __restrict__ fc_h_w, const float* __restrict__ fc_h_b,
    const float* __restrict__ fc_o_w, const float* __restrict__ fc_o_b,
    float* __restrict__ out, int B, int T)
{
    const int lane = threadIdx.x;        // 0..63
    const int e    = lane & 15;          // element column (= A row within tile)
    const int g    = lane >> 4;          // k-group / D-row group
    const int base = blockIdx.x * EPB;
    int rowe = base + e; if (rowe >= B) rowe = B - 1;

    __shared__ float htab[EPB][16];      // head exchange only

    // ---- A-fragments, K-permuted, split bf16 (MFMA operands: AGPR-free) ----
    bf16x8 a0hi[4], a0lo[4], a1hi[4], a1lo[4];
    f32x4  bias0[4], bias1[4];
    #pragma unroll
    for (int m = 0; m < 4; ++m) {
        const int r = 16 * m + e;
        #pragma unroll
        for (int i = 0; i < 8; ++i) {
            const float w0 = (i < 4) ? w_ih0[r * 16 + 4 * g + i]
                                     : w_hh0[r * 16 + 4 * g + (i - 4)];
            const float w1 = (i < 4) ? w_ih1[r * 16 + 4 * g + i]
                                     : w_hh1[r * 16 + 4 * g + (i - 4)];
            a0hi[m][i] = bhi(w0);  a0lo[m][i] = bhi(w0 - hif(w0));
            a1hi[m][i] = bhi(w1);  a1lo[m][i] = bhi(w1 - hif(w1));
        }
        const int rd = 16 * m + 4 * g;
        #pragma unroll
        for (int q = 0; q < 4; ++q) {
            bias0[m][q] = b_ih0[rd + q] + b_hh0[rd + q];
            bias1[m][q] = b_ih1[rd + q] + b_hh1[rd + q];
        }
    }
    float winq[4], binq[4];
    #pragma unroll
    for (int q = 0; q < 4; ++q) { winq[q] = w_in[4 * g + q]; binq[q] = b_in[4 * g + q]; }

    // ---- state ----
    float c0[4] = {0.f, 0.f, 0.f, 0.f};
    float c1[4] = {0.f, 0.f, 0.f, 0.f};
    float h1v[4] = {0.f, 0.f, 0.f, 0.f};
    unsigned h0h0, h0h1, h0l0, h0l1;                 // h0(t) packs
    unsigned h1h0 = 0u, h1h1 = 0u, h1l0 = 0u, h1l1 = 0u;   // h1(t-1) packs

    const float* xrow = x + (size_t)rowe * T;

    // ---- prologue: L0 at t=0 (h0_{-1}=0) ----
    {
        const float xv = xrow[0];
        float xq[4];
        #pragma unroll
        for (int q = 0; q < 4; ++q) xq[q] = fmaxf(fmaf(xv, winq[q], binq[q]), 0.0f);
        const bf16x8 Bh = mkfrag(pk2hi(xq[0], xq[1]), pk2hi(xq[2], xq[3]), 0u, 0u);
        const bf16x8 Bl = mkfrag(pk2lo(xq[0], xq[1]), pk2lo(xq[2], xq[3]), 0u, 0u);
        f32x4 acc[4];
        GATES(acc, a0hi, a0lo, bias0, Bh, Bl);
        float h0v[4];
        COMBINE(acc, c0, h0v);
        h0h0 = pk2hi(h0v[0], h0v[1]); h0h1 = pk2hi(h0v[2], h0v[3]);
        h0l0 = pk2lo(h0v[0], h0v[1]); h0l1 = pk2lo(h0v[2], h0v[3]);
    }

    float xv1 = xrow[(T > 1) ? 1 : 0];               // x(t+1) for the loop

    // ---- steady state: iteration t does  L1(t)  ||  L0(t+1)  (independent) ----
    for (int t = 0; t < T - 1; ++t) {
        const int tn = (t + 2 < T) ? (t + 2) : (T - 1);
        const float xn = xrow[tn];                   // prefetch x(t+2)

        // xi(t+1) from xv1
        float xq[4];
        #pragma unroll
        for (int q = 0; q < 4; ++q) xq[q] = fmaxf(fmaf(xv1, winq[q], binq[q]), 0.0f);

        // B-frags (both built from current h0(t) packs — before overwrite)
        const bf16x8 B0h = mkfrag(pk2hi(xq[0], xq[1]), pk2hi(xq[2], xq[3]), h0h0, h0h1);
        const bf16x8 B0l = mkfrag(pk2lo(xq[0], xq[1]), pk2lo(xq[2], xq[3]), h0l0, h0l1);
        const bf16x8 B1h = mkfrag(h0h0, h0h1, h1h0, h1h1);
        const bf16x8 B1l = mkfrag(h0l0, h0l1, h1l0, h1l1);

        // issue both layers' MFMAs back-to-back (independent acc sets)
        f32x4 acc0[4], acc1[4];
        GATES(acc0, a0hi, a0lo, bias0, B0h, B0l);    // L0(t+1)
        GATES(acc1, a1hi, a1lo, bias1, B1h, B1l);    // L1(t)

        // combines interleave: acc0's MFMA latency hides under acc1 issue & v.v.
        float h0v[4];
        COMBINE(acc0, c0, h0v);                      // h0(t+1)
        COMBINE(acc1, c1, h1v);                      // h1(t)

        h0h0 = pk2hi(h0v[0], h0v[1]); h0h1 = pk2hi(h0v[2], h0v[3]);
        h0l0 = pk2lo(h0v[0], h0v[1]); h0l1 = pk2lo(h0v[2], h0v[3]);
        h1h0 = pk2hi(h1v[0], h1v[1]); h1h1 = pk2hi(h1v[2], h1v[3]);
        h1l0 = pk2lo(h1v[0], h1v[1]); h1l1 = pk2lo(h1v[2], h1v[3]);
        xv1 = xn;
    }

    // ---- epilogue: L1(T-1) from h0(T-1), h1(T-2) ----
    {
        const bf16x8 Bh = mkfrag(h0h0, h0h1, h1h0, h1h1);
        const bf16x8 Bl = mkfrag(h0l0, h0l1, h1l0, h1l1);
        f32x4 acc[4];
        GATES(acc, a1hi, a1lo, bias1, Bh, Bl);
        COMBINE(acc, c1, h1v);                       // final h1
    }

    // ---- head: fc_h (16->8) + ReLU, fc_o (8->1) ----
    *(float4*)&htab[e][4 * g] = make_float4(h1v[0], h1v[1], h1v[2], h1v[3]);
    __syncthreads();
    if (lane < EPB) {
        const int ee = lane;
        float hv[16];
        #pragma unroll
        for (int k = 0; k < 16; ++k) hv[k] = htab[ee][k];
        float z[8];
        #pragma unroll
        for (int p = 0; p < 8; ++p) {
            float acc = fc_h_b[p];
            #pragma unroll
            for (int k = 0; k < 16; ++k) acc = fmaf(fc_h_w[p * 16 + k], hv[k], acc);
            z[p] = fmaxf(acc, 0.0f);
        }
        float o = fc_o_b[0];
        #pragma unroll
        for (int p = 0; p < 8; ++p) o = fmaf(fc_o_w[p], z[p], o);
        if (base + ee < B) out[base + ee] = o;
    }
}

extern "C" void kernel_launch(void* const* d_in, const int* in_sizes, int n_in,
                              void* d_out, int out_size, void* d_ws, size_t ws_size,
                              hipStream_t stream) {
    const float* x      = (const float*)d_in[0];
    const float* w_in   = (const float*)d_in[1];
    const float* b_in   = (const float*)d_in[2];
    const float* w_ih0  = (const float*)d_in[3];
    const float* w_hh0  = (const float*)d_in[4];
    const float* b_ih0  = (const float*)d_in[5];
    const float* b_hh0  = (const float*)d_in[6];
    const float* w_ih1  = (const float*)d_in[7];
    const float* w_hh1  = (const float*)d_in[8];
    const float* b_ih1  = (const float*)d_in[9];
    const float* b_hh1  = (const float*)d_in[10];
    const float* fc_h_w = (const float*)d_in[11];
    const float* fc_h_b = (const float*)d_in[12];
    const float* fc_o_w = (const float*)d_in[13];
    const float* fc_o_b = (const float*)d_in[14];

    const int B = out_size;                 // x is [B,T,1]
    const int T = in_sizes[0] / (B > 0 ? B : 1);
    const int grid = (B + EPB - 1) / EPB;   // 512 blocks at B=8192

    hipLaunchKernelGGL(lstm_swp, dim3(grid), dim3(64), 0, stream,
                       x, w_in, b_in, w_ih0, w_hh0, b_ih0, b_hh0,
                       w_ih1, w_hh1, b_ih1, b_hh1, fc_h_w, fc_h_b,
                       fc_o_w, fc_o_b, (float*)d_out, B, T);
}